// Round 6
// baseline (438.312 us; speedup 1.0000x reference)
//
#include <hip/hip_runtime.h>

typedef __bf16 bf16;
typedef __attribute__((ext_vector_type(8))) __bf16 bf16x8;
typedef __attribute__((ext_vector_type(4))) float f32x4;

// Problem constants
constexpr int kS   = 2048;
constexpr int kNH  = 16;
constexpr int kNKV = 8;
constexpr int kD   = 128;
constexpr int kNqkv = 4096;   // NH*D + 2*NKV*D

// ---------------------------------------------------------------------------
// async global->LDS, 16 B per lane. LDS dest is wave-uniform base + lane*16.
// ---------------------------------------------------------------------------
__device__ __forceinline__ void async_copy16(void* lds_base_uniform, const void* g) {
  __builtin_amdgcn_global_load_lds(
      (const __attribute__((address_space(1))) void*)g,
      (__attribute__((address_space(3))) void*)lds_base_uniform, 16, 0, 0);
}

// ---------------------------------------------------------------------------
// Dtype detector: flag=1 if inputs are float32, 0 if bf16 (verified R2: f32).
// ---------------------------------------------------------------------------
__global__ void detect_dtype(const unsigned short* __restrict__ hs, int* __restrict__ flag) {
  __shared__ int cnt;
  if (threadIdx.x == 0) cnt = 0;
  __syncthreads();
  int local = 0;
  for (int i = threadIdx.x; i < 65536; i += 256) {
    int e = (hs[i] >> 7) & 0xFF;
    local += (e >= 0x85) ? 1 : 0;
  }
  atomicAdd(&cnt, local);
  __syncthreads();
  if (threadIdx.x == 0) flag[0] = (cnt > 256) ? 1 : 0;
}

__device__ __forceinline__ float ld_elem(const void* p, size_t i, int f32) {
  return f32 ? ((const float*)p)[i] : (float)((const bf16*)p)[i];
}

__device__ __forceinline__ bf16x8 load8(const void* base, size_t eoff, int f32) {
  if (f32) {
    const float* p = (const float*)base + eoff;
    f32x4 a = *(const f32x4*)p;
    f32x4 b = *(const f32x4*)(p + 4);
    bf16x8 r;
    r[0]=(bf16)a[0]; r[1]=(bf16)a[1]; r[2]=(bf16)a[2]; r[3]=(bf16)a[3];
    r[4]=(bf16)b[0]; r[5]=(bf16)b[1]; r[6]=(bf16)b[2]; r[7]=(bf16)b[3];
    return r;
  }
  return *(const bf16x8*)((const bf16*)base + eoff);
}

// ---------------------------------------------------------------------------
// hs (f32 or bf16 per flag) -> bf16, so gemm1 can use the pure async path.
// ---------------------------------------------------------------------------
__global__ void convert_hs(const void* __restrict__ hs, bf16* __restrict__ out,
                           const int* __restrict__ flagp) {
  const int f32 = flagp[0];
  const size_t i = ((size_t)blockIdx.x * 256 + threadIdx.x) * 8;
  *(bf16x8*)(out + i) = load8(hs, i, f32);
}

// ---------------------------------------------------------------------------
// Weight transpose: W (K x N) row-major -> WT (N x K) row-major, K = 2048.
// One dispatch, z = 0..3 (Wq, Wk, Wv -> WQKVT; Wo -> WOT).
// ---------------------------------------------------------------------------
__global__ void transpose_weights(const void* __restrict__ Wq, const void* __restrict__ Wk,
                                  const void* __restrict__ Wv, const void* __restrict__ Wo,
                                  bf16* __restrict__ WQKVT, bf16* __restrict__ WOT,
                                  const int* __restrict__ flagp) {
  __shared__ bf16 tb[64][65];
  const int f32 = flagp[0];
  const int which = blockIdx.z;
  const void* src; bf16* dst; int N; int nbase;
  if      (which == 0) { src = Wq; dst = WQKVT; N = 2048; nbase = 0;    }
  else if (which == 1) { src = Wk; dst = WQKVT; N = 1024; nbase = 2048; }
  else if (which == 2) { src = Wv; dst = WQKVT; N = 1024; nbase = 3072; }
  else                 { src = Wo; dst = WOT;   N = 2048; nbase = 0;    }
  const int n0 = blockIdx.x * 64;
  if (n0 >= N) return;                 // uniform early-out, before any barrier
  const int k0 = blockIdx.y * 64;
  const int tx = threadIdx.x & 63, ty = threadIdx.x >> 6;
#pragma unroll
  for (int i = 0; i < 16; ++i) {
    int ks = ty + 4*i;
    tb[ks][tx] = (bf16)ld_elem(src, (size_t)(k0 + ks) * N + n0 + tx, f32);
  }
  __syncthreads();
#pragma unroll
  for (int i = 0; i < 16; ++i) {
    int ns = ty + 4*i;
    dst[(size_t)(nbase + n0 + ns) * 2048 + k0 + tx] = tb[tx][ns];
  }
}

__global__ void concat_bias(const void* __restrict__ bq, const void* __restrict__ bk,
                            const void* __restrict__ bv, bf16* __restrict__ bias,
                            const int* __restrict__ flagp) {
  const int f32 = flagp[0];
  int i = blockIdx.x * 256 + threadIdx.x;
  float v;
  if (i < 2048)      v = ld_elem(bq, i, f32);
  else if (i < 3072) v = ld_elem(bk, i - 2048, f32);
  else               v = ld_elem(bv, i - 3072, f32);
  bias[i] = (bf16)v;
}

// ---------------------------------------------------------------------------
// GEMM: C(MxN) = A(MxK) * BT(NxK)^T + bias, f32 accum. A,BT bf16.
// 128x128 tile, BK=32, 256 threads, single-barrier double-buffered async
// K-loop. ROUND 6: corrected LDS swizzle. Row = 64 B = 16 banks, so the
// bank-group of a fragment lane is (l16&1)*4 + chunk&3; placing global
// chunk j at position j ^ ((row>>1)&3) makes the 16 lanes of each quad
// cover all 8 four-bank groups exactly twice -> 2-way (free, m136).
// Staging side: chunk c holds global group (c&3) ^ ((c>>3)&3).
// ---------------------------------------------------------------------------
__global__ __launch_bounds__(256) void gemm_bt_kernel(
    const bf16* __restrict__ A, const bf16* __restrict__ BT,
    const bf16* __restrict__ bias, void* __restrict__ C, int N, int K,
    const int* __restrict__ flagp, int c_ext) {
  const int cfl = c_ext ? flagp[0] : 0;
  __shared__ bf16 lds_a[2][128 * 32];
  __shared__ bf16 lds_b[2][128 * 32];
  const int t    = threadIdx.x;
  const int lane = t & 63;
  const int wv   = t >> 6;
  const int wm   = wv & 1, wn = wv >> 1;
  const int quad = lane >> 4, l16 = lane & 15;
  const int m0 = blockIdx.y * 128;
  const int n0 = blockIdx.x * 128;

  f32x4 zero = {0.f, 0.f, 0.f, 0.f};
  f32x4 acc[4][4];
#pragma unroll
  for (int i = 0; i < 4; ++i)
#pragma unroll
    for (int j = 0; j < 4; ++j) acc[i][j] = zero;

  // chunk c (0..511): row = c>>2, swizzled global 8-elem group = (c&3)^((c>>3)&3)
  const int c0 = t, c1 = t + 256;
  const int j0 = (c0 & 3) ^ ((c0 >> 3) & 3);
  const int j1 = (c1 & 3) ^ ((c1 >> 3) & 3);
  const size_t aoff0 = (size_t)(m0 + (c0 >> 2)) * K + j0 * 8;
  const size_t aoff1 = (size_t)(m0 + (c1 >> 2)) * K + j1 * 8;
  const size_t boff0 = (size_t)(n0 + (c0 >> 2)) * K + j0 * 8;
  const size_t boff1 = (size_t)(n0 + (c1 >> 2)) * K + j1 * 8;
  const int rb0 = (t & ~63) * 8;
  const int rb1 = (256 + (t & ~63)) * 8;

  async_copy16(&lds_a[0][rb0], A  + aoff0);
  async_copy16(&lds_a[0][rb1], A  + aoff1);
  async_copy16(&lds_b[0][rb0], BT + boff0);
  async_copy16(&lds_b[0][rb1], BT + boff1);

  const int swz = (l16 >> 1) & 3;          // fragment-read chunk swizzle
  const int iters = K >> 5;
  for (int it = 0; it < iters; ++it) {
    const int cur = it & 1;
    const int kb = it << 5;
    __syncthreads();
    if (it + 1 < iters) {
      const int nkb = kb + 32;
      async_copy16(&lds_a[1 - cur][rb0], A  + aoff0 + nkb);
      async_copy16(&lds_a[1 - cur][rb1], A  + aoff1 + nkb);
      async_copy16(&lds_b[1 - cur][rb0], BT + boff0 + nkb);
      async_copy16(&lds_b[1 - cur][rb1], BT + boff1 + nkb);
    }
    bf16x8 af[4], bfr[4];
#pragma unroll
    for (int i = 0; i < 4; ++i)
      af[i]  = *(const bf16x8*)(&lds_a[cur][(wm*64 + i*16 + l16) * 32 + ((quad ^ swz) * 8)]);
#pragma unroll
    for (int j = 0; j < 4; ++j)
      bfr[j] = *(const bf16x8*)(&lds_b[cur][(wn*64 + j*16 + l16) * 32 + ((quad ^ swz) * 8)]);
#pragma unroll
    for (int i = 0; i < 4; ++i)
#pragma unroll
      for (int j = 0; j < 4; ++j)
        acc[i][j] = __builtin_amdgcn_mfma_f32_16x16x32_bf16(af[i], bfr[j], acc[i][j], 0, 0, 0);
  }

#pragma unroll
  for (int j = 0; j < 4; ++j) {
    const int col = n0 + wn*64 + j*16 + l16;
    const float bvf = bias ? (float)bias[col] : 0.0f;
#pragma unroll
    for (int i = 0; i < 4; ++i) {
      const int rowb = m0 + wm*64 + i*16 + quad*4;
#pragma unroll
      for (int r = 0; r < 4; ++r) {
        const float v = acc[i][j][r] + bvf;
        const size_t idx = (size_t)(rowb + r) * N + col;
        if (cfl) ((float*)C)[idx] = v;
        else     ((bf16*)C)[idx]  = (bf16)v;
      }
    }
  }
}

// ---------------------------------------------------------------------------
// RoPE in place on Q (cols 0..2047) and K (cols 2048..3071) of C1.
// ---------------------------------------------------------------------------
__global__ void rope_kernel(bf16* __restrict__ C1) {
  const int tx = threadIdx.x & 63, ty = threadIdx.x >> 6;
  const int row = blockIdx.x * 4 + ty;
  const int hh = blockIdx.y;
  const int col = (hh < kNH) ? hh * kD : kNH*kD + (hh - kNH) * kD;
  const int s = row & (kS - 1);
  const float freq = __expf(-(float)tx * (13.815510557964274f / 64.0f));
  const float ang = (float)s * freq;
  const float c = cosf(ang), sn = sinf(ang);
  const size_t base = (size_t)row * kNqkv + col;
  const float x1 = (float)C1[base + tx];
  const float x2 = (float)C1[base + 64 + tx];
  C1[base + tx]      = (bf16)(x1 * c - x2 * sn);
  C1[base + 64 + tx] = (bf16)(x2 * c + x1 * sn);
}

// ---------------------------------------------------------------------------
// V transpose: VT[b][kv][d][t] = C1[b*S+t][3072 + kv*128 + d]
// ---------------------------------------------------------------------------
__global__ void v_transpose(const bf16* __restrict__ C1, bf16* __restrict__ VT) {
  __shared__ bf16 tb[64][65];
  const int bkv = blockIdx.z;
  const int b = bkv >> 3, kv = bkv & 7;
  const int t0 = blockIdx.x * 64, d0 = blockIdx.y * 64;
  const int tx = threadIdx.x & 63, ty = threadIdx.x >> 6;
#pragma unroll
  for (int i = 0; i < 16; ++i) {
    int ts = ty + 4*i;
    tb[ts][tx] = C1[(size_t)(b*kS + t0 + ts) * kNqkv + 3072 + kv*kD + d0 + tx];
  }
  __syncthreads();
  const size_t obase = ((size_t)(b*kNKV + kv) * kD) * kS;
#pragma unroll
  for (int i = 0; i < 16; ++i) {
    int ds = ty + 4*i;
    VT[obase + (size_t)(d0 + ds) * kS + t0 + tx] = tb[tx][ds];
  }
}

// ---------------------------------------------------------------------------
// Flash attention, causal GQA, fixed-shift softmax; causal pairing + double-
// buffered async K/V staging (R5 structure, 125.6 -> <111 us).
// ---------------------------------------------------------------------------
__global__ __launch_bounds__(256) void attn_kernel(
    const bf16* __restrict__ C1, const bf16* __restrict__ VT, bf16* __restrict__ CTX) {
  constexpr int LDP = 72;
  __shared__ bf16 lds_k[2][64 * 128];
  __shared__ bf16 lds_v[2][128 * 64];
  __shared__ bf16 lds_p[4][16 * LDP];
  const int p = blockIdx.x, h = blockIdx.y, b = blockIdx.z;
  const int qtA = 31 - p;                     // big q-tile
  const int qtB = p;                          // small q-tile
  const int kvh = h >> 1;                     // G = 2
  const int t = threadIdx.x, lane = t & 63, wv = t >> 6;
  const int quad = lane >> 4, l16 = lane & 15;
  const float SC2 = 0.08838834764831845f * 1.4426950408889634f; // scale*log2(e)

  bf16x8 qfA[4], qfB[4];
  {
    const size_t rowQA = (size_t)(b*kS + qtA*64 + wv*16 + l16) * kNqkv + h * kD;
    const size_t rowQB = (size_t)(b*kS + qtB*64 + wv*16 + l16) * kNqkv + h * kD;
#pragma unroll
    for (int c = 0; c < 4; ++c) {
      qfA[c] = *(const bf16x8*)(C1 + rowQA + c*32 + quad*8);
      qfB[c] = *(const bf16x8*)(C1 + rowQB + c*32 + quad*8);
    }
  }

  float lA[4] = {0,0,0,0}, lB[4] = {0,0,0,0};
  f32x4 oA[8], oB[8];
  f32x4 zero = {0.f, 0.f, 0.f, 0.f};
#pragma unroll
  for (int n = 0; n < 8; ++n) { oA[n] = zero; oB[n] = zero; }

  const int qrowA = qtA*64 + wv*16 + quad*4;
  const int qrowB = qtB*64 + wv*16 + quad*4;
  bf16* pw = &lds_p[wv][0];

  const size_t kbase = (size_t)b * kS * kNqkv + 2048 + kvh * kD;
  const size_t vbase = ((size_t)(b*kNKV + kvh) * kD) * kS;
  const int jv = (lane & 7) ^ ((lane >> 3) & 7);

  auto stage = [&](int buf, int k0) {
#pragma unroll
    for (int s2 = 0; s2 < 4; ++s2) {
      const int r = wv + s2 * 4;
      const int krow = r*4 + (lane >> 4);
      const int jk = (lane & 15) ^ (krow & 7);
      async_copy16(&lds_k[buf][r * 512], C1 + kbase + (size_t)(k0 + krow) * kNqkv + jk * 8);
      const int vrow = r*8 + (lane >> 3);
      async_copy16(&lds_v[buf][r * 512], VT + vbase + (size_t)vrow * kS + k0 + jv * 8);
    }
  };

  auto compute = [&](const bf16* kb_, const bf16* vb_, const bf16x8* qf,
                     f32x4* o_acc, float* l_acc, int qrow_base, int k0, bool diag) {
    f32x4 sc4[4];
#pragma unroll
    for (int g = 0; g < 4; ++g) {
      f32x4 s_acc = zero;
#pragma unroll
      for (int c = 0; c < 4; ++c) {
        bf16x8 kf = *(const bf16x8*)(kb_ + (g*16 + l16) * 128 + (((c*4 + quad) ^ (l16 & 7)) * 8));
        s_acc = __builtin_amdgcn_mfma_f32_16x16x32_bf16(qf[c], kf, s_acc, 0, 0, 0);
      }
      sc4[g] = s_acc;
    }
#pragma unroll
    for (int g = 0; g < 4; ++g) {
#pragma unroll
      for (int r = 0; r < 4; ++r) {
        float pv = __builtin_amdgcn_exp2f(fmaf(sc4[g][r], SC2, -24.f));
        if (diag && (k0 + g*16 + l16 > qrow_base + r)) pv = 0.f;
        l_acc[r] += pv;
        pw[(quad*4 + r) * LDP + g*16 + l16] = (bf16)pv;
      }
    }
    __builtin_amdgcn_wave_barrier();   // DS pipe in-order per wave: write->read
#pragma unroll
    for (int kk = 0; kk < 2; ++kk) {
      bf16x8 pf = *(const bf16x8*)(pw + l16 * LDP + kk*32 + quad*8);
#pragma unroll
      for (int n = 0; n < 8; ++n) {
        bf16x8 vf = *(const bf16x8*)(vb_ + (n*16 + l16) * 64 + (((kk*4 + quad) ^ (l16 & 7)) * 8));
        o_acc[n] = __builtin_amdgcn_mfma_f32_16x16x32_bf16(pf, vf, o_acc[n], 0, 0, 0);
      }
    }
    __builtin_amdgcn_wave_barrier();   // later P writes stay after these reads
  };

  stage(0, 0);
  for (int kt = 0; kt <= qtA; ++kt) {
    const int cur = kt & 1;
    __syncthreads();                   // drain buf[cur] copies; all waves done with buf[1-cur]
    if (kt + 1 <= qtA) stage(1 - cur, (kt + 1) * 64);
    const int k0 = kt * 64;
    compute(&lds_k[cur][0], &lds_v[cur][0], qfA, oA, lA, qrowA, k0, kt == qtA);
    if (kt <= qtB)
      compute(&lds_k[cur][0], &lds_v[cur][0], qfB, oB, lB, qrowB, k0, kt == qtB);
  }

  float invA[4], invB[4];
#pragma unroll
  for (int r = 0; r < 4; ++r) {
    float la = lA[r], lb = lB[r];
    la += __shfl_xor(la, 1); lb += __shfl_xor(lb, 1);
    la += __shfl_xor(la, 2); lb += __shfl_xor(lb, 2);
    la += __shfl_xor(la, 4); lb += __shfl_xor(lb, 4);
    la += __shfl_xor(la, 8); lb += __shfl_xor(lb, 8);
    invA[r] = 1.0f / la;     invB[r] = 1.0f / lb;
  }
#pragma unroll
  for (int n = 0; n < 8; ++n) {
#pragma unroll
    for (int r = 0; r < 4; ++r) {
      CTX[(size_t)(b*kS + qrowA + r) * (kNH*kD) + h*kD + n*16 + l16] = (bf16)(oA[n][r] * invA[r]);
      CTX[(size_t)(b*kS + qrowB + r) * (kNH*kD) + h*kD + n*16 + l16] = (bf16)(oB[n][r] * invB[r]);
    }
  }
}

// ---------------------------------------------------------------------------
// Workspace layout (liveness-overlapped; peak ~72 MB):
//   C1    [0,32M)   gemm1->attn
//   WQKVT [32M,48M) start->gemm1     VT [32M,40M) v_transpose->attn (after)
//   WOT   [48M,56M) start->gemm2
//   HSB   [56M,72M) convert->gemm1   CTX [56M,72M) attn->gemm2 (after)
//   BIAS  [72M,+8K), FLAG [72M+8K)
// ---------------------------------------------------------------------------
extern "C" void kernel_launch(void* const* d_in, const int* in_sizes, int n_in,
                              void* d_out, int out_size, void* d_ws, size_t ws_size,
                              hipStream_t stream) {
  const void* hs = d_in[0];
  const void* Wq = d_in[1];
  const void* bq = d_in[2];
  const void* Wk = d_in[3];
  const void* bk = d_in[4];
  const void* Wv = d_in[5];
  const void* bv = d_in[6];
  const void* Wo = d_in[7];

  char* ws = (char*)d_ws;
  bf16* C1    = (bf16*)(ws + 0);
  bf16* WQKVT = (bf16*)(ws + 33554432);
  bf16* VT    = (bf16*)(ws + 33554432);
  bf16* WOT   = (bf16*)(ws + 50331648);
  bf16* HSB   = (bf16*)(ws + 58720256);
  bf16* CTX   = (bf16*)(ws + 58720256);
  bf16* BIAS  = (bf16*)(ws + 75497472);
  int*  FLAG  = (int*) (ws + 75505664);

  detect_dtype<<<1, 256, 0, stream>>>((const unsigned short*)hs, FLAG);
  transpose_weights<<<dim3(32, 32, 4), 256, 0, stream>>>(Wq, Wk, Wv, Wo, WQKVT, WOT, FLAG);
  convert_hs<<<4096, 256, 0, stream>>>(hs, HSB, FLAG);
  concat_bias<<<16, 256, 0, stream>>>(bq, bk, bv, BIAS, FLAG);
  gemm_bt_kernel<<<dim3(32, 32), 256, 0, stream>>>(HSB, WQKVT, BIAS, C1, 4096, 2048, FLAG, 0);
  rope_kernel<<<dim3(1024, 24), 256, 0, stream>>>(C1);
  v_transpose<<<dim3(32, 2, 16), 256, 0, stream>>>(C1, VT);
  attn_kernel<<<dim3(16, 16, 2), 256, 0, stream>>>(C1, VT, CTX);
  gemm_bt_kernel<<<dim3(16, 32), 256, 0, stream>>>(CTX, WOT, nullptr, d_out, 2048, 2048, FLAG, 1);
}